// Round 5
// baseline (688.163 us; speedup 1.0000x reference)
//
#include <hip/hip_runtime.h>
#include <math.h>

#define D 64
#define H 128
#define KIN 8
#define KOUT 4
#define THREADS 256
#define WAVES 4
#define XLDB 132               // xbuf row stride (264B): 2-way worst on b128 reads
#define ELD16 72               // eins row stride (144B), rows 16B-aligned

typedef __attribute__((ext_vector_type(8))) short short8v;  // 8 bf16 = 4 VGPR
typedef __attribute__((ext_vector_type(4))) float f32x4;

__device__ inline unsigned short f2bf(float f) {            // RNE float->bf16
    union { float f; unsigned u; } v; v.f = f;
    unsigned r = v.u + 0x7FFF + ((v.u >> 16) & 1);
    return (unsigned short)(r >> 16);
}

// ---- weight pre-conversion: W0,W1 (fp32, 128x128 each) -> bf16 in ws ----
__global__ void convert_w_kernel(const float* __restrict__ W0,
                                 const float* __restrict__ W1,
                                 unsigned short* __restrict__ Wbf) {
    const int i = blockIdx.x * 256 + threadIdx.x;           // 0 .. 32767
    const float v = (i < H*H) ? W0[i] : W1[i - H*H];
    Wbf[i] = f2bf(v);
}

__global__ __launch_bounds__(THREADS, 6) void encoder_kernel(
    const float* __restrict__ edges,
    const int*   __restrict__ in_idx,
    const int*   __restrict__ in_mask,
    const int*   __restrict__ out_idx,
    const int*   __restrict__ out_mask,
    const float* __restrict__ b0, const float* __restrict__ b1,
    const float* __restrict__ Wout, const float* __restrict__ bout,
    const unsigned short* __restrict__ Wbf,   // [2][128][128] bf16
    float* __restrict__ out, int N)
{
    // wave-private slices; NO __syncthreads in this kernel
    __shared__ __align__(16) unsigned short xbuf[WAVES][16][XLDB]; // 16896 B
    __shared__ __align__(16) unsigned short eins[WAVES][16][ELD16]; // 9216 B

    const int tid  = threadIdx.x;
    const int wave = tid >> 6;
    const int lane = tid & 63;
    const int col  = lane & 15;
    const int grp  = lane >> 4;
    const int n0   = blockIdx.x * 16 + wave * 4;   // this wave's 4 nodes (N%16==0)

    // ---------------- upfront index/mask loads ----------------
    const int   idxA = in_idx [(size_t)(n0+0)*KIN + col];   // pair A: nodes n0,n0+1
    const int   idxB = in_idx [(size_t)(n0+2)*KIN + col];   // pair B: nodes n0+2,n0+3
    const float mkA  = (float)in_mask[(size_t)(n0+0)*KIN + col];
    const float mkB  = (float)in_mask[(size_t)(n0+2)*KIN + col];
    const int   oidx = out_idx[(size_t)n0*KOUT + col];      // 16 out-edges (4 nodes)
    const float omsk = (float)out_mask[(size_t)n0*KOUT + (lane >> 2)];

    // ---------------- all 48 edge-row gathers issued upfront ----------------
    float einA[16], einB[16], eout[16];
    #pragma unroll
    for (int r = 0; r < 16; ++r) einA[r] = edges[(size_t)__shfl(idxA, r) * D + lane];
    #pragma unroll
    for (int r = 0; r < 16; ++r) einB[r] = edges[(size_t)__shfl(idxB, r) * D + lane];
    #pragma unroll
    for (int r = 0; r < 16; ++r) eout[r] = edges[(size_t)__shfl(oidx, r) * D + lane];

    // out-edge rows -> xbuf (consumed only by phase 2)
    #pragma unroll
    for (int r = 0; r < 16; ++r) xbuf[wave][r][lane] = f2bf(eout[r]);

    // ---------------- attention + pooling, one node-pair at a time ----------
    auto do_pair = [&](const float* einr, const float mkcol, const int xrow0) {
        #pragma unroll
        for (int r = 0; r < 16; ++r) eins[wave][r][lane] = f2bf(einr[r]);
        const short8v f0 = *(const short8v*)&eins[wave][col][grp*8];
        const short8v f1 = *(const short8v*)&eins[wave][col][32 + grp*8];
        f32x4 sc = (f32x4){0.f, 0.f, 0.f, 0.f};
        sc = __builtin_amdgcn_mfma_f32_16x16x32_bf16(f0, f0, sc, 0, 0, 0);
        sc = __builtin_amdgcn_mfma_f32_16x16x32_bf16(f1, f1, sc, 0, 0, 0);

        // mask: cross-node blocks + masked keys -> -1e9   (row=grp*4+j, col)
        float s0, s1, s2, s3;
        {
            const bool kv = (mkcol > 0.f);
            #define MSK(jj, sv) { const int row = grp*4 + jj; \
                const bool ok = kv && ((row < 8) == (col < 8)); \
                sv = ok ? sc[jj] * 0.125f : -1e9f; }
            MSK(0, s0) MSK(1, s1) MSK(2, s2) MSK(3, s3)
            #undef MSK
        }
        // softmax over cols (16 lanes), 4 rows in flight
        float m0=s0, m1=s1, m2=s2, m3=s3;
        #pragma unroll
        for (int off = 1; off < 16; off <<= 1) {
            m0 = fmaxf(m0, __shfl_xor(m0, off));
            m1 = fmaxf(m1, __shfl_xor(m1, off));
            m2 = fmaxf(m2, __shfl_xor(m2, off));
            m3 = fmaxf(m3, __shfl_xor(m3, off));
        }
        float e0=__expf(s0-m0), e1=__expf(s1-m1), e2=__expf(s2-m2), e3=__expf(s3-m3);
        float t0=e0, t1=e1, t2=e2, t3=e3;
        #pragma unroll
        for (int off = 1; off < 16; off <<= 1) {
            t0 += __shfl_xor(t0, off); t1 += __shfl_xor(t1, off);
            t2 += __shfl_xor(t2, off); t3 += __shfl_xor(t3, off);
        }
        // w[col] = sum_q maskq * attn[q][col]
        float wsum = __shfl(mkcol, grp*4 + 0) * (e0 / t0)
                   + __shfl(mkcol, grp*4 + 1) * (e1 / t1)
                   + __shfl(mkcol, grp*4 + 2) * (e2 / t2)
                   + __shfl(mkcol, grp*4 + 3) * (e3 / t3);
        wsum += __shfl_xor(wsum, 16);
        wsum += __shfl_xor(wsum, 32);

        // denom per node
        float dn = mkcol;
        dn += __shfl_xor(dn, 1); dn += __shfl_xor(dn, 2); dn += __shfl_xor(dn, 4);
        const float dnA = fmaxf(__shfl(dn, 0), 1.f);
        const float dnB = fmaxf(__shfl(dn, 8), 1.f);

        // pooled from registers (fp32), lane = d
        float pA = 0.f, pB = 0.f;
        #pragma unroll
        for (int k = 0; k < 8; ++k) {
            pA += __shfl(wsum, k)     * einr[k];
            pB += __shfl(wsum, 8 + k) * einr[8 + k];
        }
        const unsigned short pbA = f2bf(pA / dnA);
        const unsigned short pbB = f2bf(pB / dnB);
        #pragma unroll
        for (int j = 0; j < KOUT; ++j) {
            xbuf[wave][xrow0 + j]    [D + lane] = pbA;
            xbuf[wave][xrow0 + 4 + j][D + lane] = pbB;
        }
    };
    do_pair(einA, mkA, 0);   // nodes n0, n0+1   -> rows 0..7
    do_pair(einB, mkB, 8);   // nodes n0+2, n0+3 -> rows 8..15

    // ---------------- Phase 2: wave-private 16x128x128 bf16-MFMA layers -----
    const int kofs = grp * 8;
    #pragma unroll
    for (int layer = 0; layer < 2; ++layer) {
        const unsigned short* __restrict__ Wl = Wbf + layer * (H*H);
        const float* __restrict__ bl = layer ? b1 : b0;

        f32x4 acc[8];
        #pragma unroll
        for (int ct = 0; ct < 8; ++ct) {
            const float bv = bl[ct*16 + col];
            acc[ct] = (f32x4){bv, bv, bv, bv};
        }
        #pragma unroll
        for (int ks = 0; ks < 4; ++ks) {
            const short8v a = *(const short8v*)&xbuf[wave][col][ks*32 + kofs];
            #pragma unroll
            for (int ct = 0; ct < 8; ++ct) {
                const short8v bf = *(const short8v*)&Wl[(size_t)(ct*16 + col)*H + ks*32 + kofs];
                acc[ct] = __builtin_amdgcn_mfma_f32_16x16x32_bf16(a, bf, acc[ct], 0, 0, 0);
            }
        }
        // in-wave instruction order guarantees all reads precede these writes
        #pragma unroll
        for (int ct = 0; ct < 8; ++ct)
            #pragma unroll
            for (int j = 0; j < 4; ++j)
                xbuf[wave][grp*4 + j][ct*16 + col] = f2bf(fmaxf(acc[ct][j], 0.f));
    }

    // ---------------- epilogue: y = h1 . Wout + bout, masked ----------------
    {
        const int row = lane >> 2;         // 0..15 (wave-local MLP row)
        const int kq  = lane & 3;          // k-quarter (32 each)
        float p = 0.f;
        #pragma unroll
        for (int m = 0; m < 4; ++m) {
            const int k0 = kq*32 + m*8;
            const short8v hv = *(const short8v*)&xbuf[wave][row][k0];
            const float4 w0 = *(const float4*)&Wout[k0];
            const float4 w1 = *(const float4*)&Wout[k0 + 4];
            union { unsigned u; float f; } c;
            float acc8 = 0.f;
            c.u = ((unsigned)(unsigned short)hv[0]) << 16; acc8 += c.f * w0.x;
            c.u = ((unsigned)(unsigned short)hv[1]) << 16; acc8 += c.f * w0.y;
            c.u = ((unsigned)(unsigned short)hv[2]) << 16; acc8 += c.f * w0.z;
            c.u = ((unsigned)(unsigned short)hv[3]) << 16; acc8 += c.f * w0.w;
            c.u = ((unsigned)(unsigned short)hv[4]) << 16; acc8 += c.f * w1.x;
            c.u = ((unsigned)(unsigned short)hv[5]) << 16; acc8 += c.f * w1.y;
            c.u = ((unsigned)(unsigned short)hv[6]) << 16; acc8 += c.f * w1.z;
            c.u = ((unsigned)(unsigned short)hv[7]) << 16; acc8 += c.f * w1.w;
            p += acc8;
        }
        p += __shfl_xor(p, 1);
        p += __shfl_xor(p, 2);
        if (kq == 0) {
            const long long grow = (long long)n0 * KOUT + row;
            if (grow < (long long)N * KOUT)
                out[grow] = (p + bout[0]) * omsk;
        }
    }
}

extern "C" void kernel_launch(void* const* d_in, const int* in_sizes, int n_in,
                              void* d_out, int out_size, void* d_ws, size_t ws_size,
                              hipStream_t stream)
{
    const float* edges  = (const float*)d_in[0];
    const int* in_idx   = (const int*)d_in[1];
    const int* in_mask  = (const int*)d_in[2];
    const int* out_idx  = (const int*)d_in[3];
    const int* out_mask = (const int*)d_in[4];
    const float* W0   = (const float*)d_in[5];
    const float* b0   = (const float*)d_in[6];
    const float* W1   = (const float*)d_in[7];
    const float* b1   = (const float*)d_in[8];
    const float* Wout = (const float*)d_in[9];
    const float* bout = (const float*)d_in[10];
    float* out = (float*)d_out;
    unsigned short* Wbf = (unsigned short*)d_ws;   // 2*128*128 bf16 = 64 KB

    const int nNodes = in_sizes[1] / KIN;               // 200000
    convert_w_kernel<<<(2*H*H + 255) / 256, 256, 0, stream>>>(W0, W1, Wbf);
    const int grid = (nNodes + 15) / 16;                // 12500 (16 nodes/block)
    encoder_kernel<<<grid, THREADS, 0, stream>>>(
        edges, in_idx, in_mask, out_idx, out_mask,
        b0, b1, Wout, bout, Wbf, out, nNodes);
}

// Round 8
// 684.739 us; speedup vs baseline: 1.0050x; 1.0050x over previous
//
#include <hip/hip_runtime.h>
#include <math.h>

#define D 64
#define H 128
#define KIN 8
#define KOUT 4
#define NPB 8                  // nodes per block (halved: shorter per-wave chain)
#define ROWS (NPB*KOUT)        // 32 MLP rows per block
#define THREADS 256
#define WAVES 4
#define NPW (NPB/WAVES)        // 2 nodes per wave
#define XLDB 136               // xbuf leading dim bf16 (272B/row: 2-way reads, free)
#define ELD 68                 // eins leading dim fp32 (64+4)

typedef __attribute__((ext_vector_type(8))) short short8v;  // 8 bf16 = 4 VGPR
typedef __attribute__((ext_vector_type(4))) float f32x4;

__device__ inline unsigned short f2bf(float f) {            // RNE float->bf16
    union { float f; unsigned u; } v; v.f = f;
    unsigned r = v.u + 0x7FFF + ((v.u >> 16) & 1);
    return (unsigned short)(r >> 16);
}
__device__ inline float bf2f(unsigned short h) {
    union { unsigned u; float f; } v; v.u = ((unsigned)h) << 16; return v.f;
}

// ---- weight pre-conversion: W0,W1 (fp32, 128x128 each) -> bf16 in ws ----
__global__ void convert_w_kernel(const float* __restrict__ W0,
                                 const float* __restrict__ W1,
                                 unsigned short* __restrict__ Wbf) {
    const int i = blockIdx.x * 256 + threadIdx.x;           // 0 .. 32767
    const float v = (i < H*H) ? W0[i] : W1[i - H*H];
    Wbf[i] = f2bf(v);
}

__global__ __launch_bounds__(THREADS, 6) void encoder_kernel(
    const float* __restrict__ edges,
    const int*   __restrict__ in_idx,
    const int*   __restrict__ in_mask,
    const int*   __restrict__ out_idx,
    const int*   __restrict__ out_mask,
    const float* __restrict__ b0, const float* __restrict__ b1,
    const float* __restrict__ Wout, const float* __restrict__ bout,
    const unsigned short* __restrict__ Wbf,   // [2][128][128] bf16 (W0bf, W1bf)
    float* __restrict__ out, int N)
{
    __shared__ unsigned short xbuf[ROWS][XLDB];   //  8704 B (x / h, bf16)
    __shared__ float eins[WAVES][KIN][ELD];       //  8704 B
    __shared__ float omaskf[ROWS];                //   128 B   => ~17.6 KB

    const int tid  = threadIdx.x;
    const int wave = tid >> 6;
    const int lane = tid & 63;
    const int nodeBase = blockIdx.x * NPB;

    // ---------------- Phase 1: attention + pooling + gathers (R2-measured-best) ----
    const int q   = lane >> 3;
    const int kk8 = lane & 7;
    for (int it = 0; it < NPW; ++it) {
        const int nl = wave * NPW + it;      // local node 0..7
        const int n  = nodeBase + nl;
        __syncthreads();
        if (n < N) {
            #pragma unroll
            for (int e = 0; e < KIN; ++e) {
                const int idx = in_idx[n*KIN + e];
                eins[wave][e][lane] = edges[(size_t)idx * D + lane];
            }
        }
        __syncthreads();
        if (n < N) {
            float denom = 0.f;
            #pragma unroll
            for (int e = 0; e < KIN; ++e) denom += (float)in_mask[n*KIN + e];
            denom = fmaxf(denom, 1.f);
            const float mk_k = (float)in_mask[n*KIN + kk8];
            const float mk_q = (float)in_mask[n*KIN + q];

            float s = 0.f;
            #pragma unroll
            for (int d4 = 0; d4 < D; d4 += 4) {
                const float4 a = *(const float4*)&eins[wave][q][d4];
                const float4 b = *(const float4*)&eins[wave][kk8][d4];
                s += a.x*b.x + a.y*b.y + a.z*b.z + a.w*b.w;
            }
            s *= 0.125f;
            if (mk_k == 0.f) s = -1e9f;

            float mx = s;
            #pragma unroll
            for (int off = 1; off < 8; off <<= 1) mx = fmaxf(mx, __shfl_xor(mx, off));
            const float ex = __expf(s - mx);
            float sum = ex;
            #pragma unroll
            for (int off = 1; off < 8; off <<= 1) sum += __shfl_xor(sum, off);

            float wk = mk_q * (ex / sum);
            #pragma unroll
            for (int off = 8; off < 64; off <<= 1) wk += __shfl_xor(wk, off);

            float p = 0.f;
            #pragma unroll
            for (int j = 0; j < KIN; ++j) p += __shfl(wk, j) * eins[wave][j][lane];
            p /= denom;
            const unsigned short pb = f2bf(p);

            #pragma unroll
            for (int j = 0; j < KOUT; ++j) {
                const int oi = out_idx[n*KOUT + j];
                xbuf[nl*KOUT + j][lane]     = f2bf(edges[(size_t)oi * D + lane]);
                xbuf[nl*KOUT + j][D + lane] = pb;
            }
            if (lane < KOUT) omaskf[nl*KOUT + lane] = (float)out_mask[n*KOUT + lane];
        }
    }
    __syncthreads();

    // ---------------- Phase 2: two 32x128x128 bf16-MFMA layers ----------------
    // wave -> 16 rows x 64 cols: 1 row-tile x 4 col-tiles of 16x16
    const int rowbase = (wave >> 1) * 16;
    const int colbase = (wave & 1) * 64;
    const int l15  = lane & 15;
    const int kofs = (lane >> 4) * 8;
    const int rrow = (lane >> 4) * 4;

    #pragma unroll
    for (int layer = 0; layer < 2; ++layer) {
        const unsigned short* __restrict__ Wl = Wbf + layer * (H*H);
        const float* __restrict__ bl = layer ? b1 : b0;

        f32x4 acc[4];
        #pragma unroll
        for (int ct = 0; ct < 4; ++ct) {
            const float bv = bl[colbase + ct*16 + l15];
            acc[ct] = (f32x4){bv, bv, bv, bv};
        }

        #pragma unroll
        for (int ks = 0; ks < 4; ++ks) {
            const short8v a = *(const short8v*)&xbuf[rowbase + l15][ks*32 + kofs];
            #pragma unroll
            for (int ct = 0; ct < 4; ++ct) {
                const short8v bf = *(const short8v*)&Wl[(size_t)(colbase + ct*16 + l15) * H + ks*32 + kofs];
                acc[ct] = __builtin_amdgcn_mfma_f32_16x16x32_bf16(a, bf, acc[ct], 0, 0, 0);
            }
        }
        __syncthreads();   // all A-reads of xbuf complete
        #pragma unroll
        for (int ct = 0; ct < 4; ++ct)
            #pragma unroll
            for (int j = 0; j < 4; ++j)
                xbuf[rowbase + rrow + j][colbase + ct*16 + l15] =
                    f2bf(fmaxf(acc[ct][j], 0.f));
        __syncthreads();
    }

    // ---------------- epilogue: y = h1 . Wout + bout, masked ----------------
    {
        const int row = tid >> 3;          // 0..31
        const int kq  = tid & 7;           // k-eighth (16 each)
        float p = 0.f;
        #pragma unroll
        for (int m = 0; m < 2; ++m) {
            const int k0 = kq*16 + m*8;
            const short8v hv = *(const short8v*)&xbuf[row][k0];
            const float4 w0 = *(const float4*)&Wout[k0];
            const float4 w1 = *(const float4*)&Wout[k0 + 4];
            p += bf2f((unsigned short)hv[0]) * w0.x + bf2f((unsigned short)hv[1]) * w0.y
               + bf2f((unsigned short)hv[2]) * w0.z + bf2f((unsigned short)hv[3]) * w0.w
               + bf2f((unsigned short)hv[4]) * w1.x + bf2f((unsigned short)hv[5]) * w1.y
               + bf2f((unsigned short)hv[6]) * w1.z + bf2f((unsigned short)hv[7]) * w1.w;
        }
        p += __shfl_xor(p, 1);
        p += __shfl_xor(p, 2);
        p += __shfl_xor(p, 4);
        if (kq == 0) {
            const long long grow = (long long)nodeBase * KOUT + row;
            if (grow < (long long)N * KOUT)
                out[grow] = (p + bout[0]) * omaskf[row];
        }
    }
}

extern "C" void kernel_launch(void* const* d_in, const int* in_sizes, int n_in,
                              void* d_out, int out_size, void* d_ws, size_t ws_size,
                              hipStream_t stream)
{
    const float* edges  = (const float*)d_in[0];
    const int* in_idx   = (const int*)d_in[1];
    const int* in_mask  = (const int*)d_in[2];
    const int* out_idx  = (const int*)d_in[3];
    const int* out_mask = (const int*)d_in[4];
    const float* W0   = (const float*)d_in[5];
    const float* b0   = (const float*)d_in[6];
    const float* W1   = (const float*)d_in[7];
    const float* b1   = (const float*)d_in[8];
    const float* Wout = (const float*)d_in[9];
    const float* bout = (const float*)d_in[10];
    float* out = (float*)d_out;
    unsigned short* Wbf = (unsigned short*)d_ws;   // 2*128*128 bf16 = 64 KB

    const int nNodes = in_sizes[1] / KIN;               // 200000
    convert_w_kernel<<<(2*H*H + 255) / 256, 256, 0, stream>>>(W0, W1, Wbf);
    const int grid = (nNodes + NPB - 1) / NPB;          // 25000
    encoder_kernel<<<grid, THREADS, 0, stream>>>(
        edges, in_idx, in_mask, out_idx, out_mask,
        b0, b1, Wout, bout, Wbf, out, nNodes);
}

// Round 11
// 588.034 us; speedup vs baseline: 1.1703x; 1.1645x over previous
//
#include <hip/hip_runtime.h>
#include <math.h>

#define D 64
#define H 128
#define KIN 8
#define KOUT 4
#define ELD16 72               // eins row stride bf16 (144B)
#define XLDB 136               // xbuf row stride bf16 (272B: 2-way b128 reads, free)
#define BROWS 128              // MLP rows per block (32 nodes)

typedef __attribute__((ext_vector_type(8))) short short8v;  // 8 bf16 = 4 VGPR
typedef __attribute__((ext_vector_type(4))) float f32x4;

__device__ inline unsigned short f2bf(float f) {            // RNE float->bf16
    union { float f; unsigned u; } v; v.f = f;
    unsigned r = v.u + 0x7FFF + ((v.u >> 16) & 1);
    return (unsigned short)(r >> 16);
}

// ---- weight pre-conversion: W0,W1 (fp32, 128x128 each) -> bf16 in ws ----
__global__ void convert_w_kernel(const float* __restrict__ W0,
                                 const float* __restrict__ W1,
                                 unsigned short* __restrict__ Wbf) {
    const int i = blockIdx.x * 256 + threadIdx.x;           // 0 .. 32767
    const float v = (i < H*H) ? W0[i] : W1[i - H*H];
    Wbf[i] = f2bf(v);
}

// ================= Kernel A: attention -> pooled[chunk][64] bf16 ============
// one wave = 2 nodes, no __syncthreads, MFMA scores (R4-verified numerics)
__global__ __launch_bounds__(256, 6) void attn_kernel(
    const float* __restrict__ edges,
    const int*   __restrict__ in_idx,
    const int*   __restrict__ in_mask,
    unsigned short* __restrict__ pooled,   // [nodeEnd-nodeBase][64] bf16
    int nodeBase, int nodeEnd)
{
    __shared__ __align__(16) unsigned short eins[4][16][ELD16]; // 9216 B
    const int tid  = threadIdx.x;
    const int wave = tid >> 6;
    const int lane = tid & 63;
    const int col  = lane & 15;
    const int grp  = lane >> 4;
    const int n0   = nodeBase + blockIdx.x * 8 + wave * 2;
    if (n0 >= nodeEnd) return;             // wave-uniform

    const int   idx_l = in_idx [(size_t)n0*KIN + col];   // 16 idx = 2 nodes
    const float mkcol = (float)in_mask[(size_t)n0*KIN + col];

    // gather 16 in-edge rows (lane = d); keep fp32 in regs for pooling
    float ein_r[16];
    #pragma unroll
    for (int r = 0; r < 16; ++r)
        ein_r[r] = edges[(size_t)__shfl(idx_l, r) * D + lane];
    #pragma unroll
    for (int r = 0; r < 16; ++r) eins[wave][r][lane] = f2bf(ein_r[r]);

    // scores for both nodes in one 16x16 tile: S = Ein . Ein^T (A==B reg)
    const short8v f0 = *(const short8v*)&eins[wave][col][grp*8];
    const short8v f1 = *(const short8v*)&eins[wave][col][32 + grp*8];
    f32x4 sc = (f32x4){0.f, 0.f, 0.f, 0.f};
    sc = __builtin_amdgcn_mfma_f32_16x16x32_bf16(f0, f0, sc, 0, 0, 0);
    sc = __builtin_amdgcn_mfma_f32_16x16x32_bf16(f1, f1, sc, 0, 0, 0);

    // mask: cross-node blocks + masked keys -> -1e9   (row=grp*4+j, col)
    float s0, s1, s2, s3;
    {
        const bool kv = (mkcol > 0.f);
        #define MSK(jj, sv) { const int row = grp*4 + jj; \
            const bool ok = kv && ((row < 8) == (col < 8)); \
            sv = ok ? sc[jj] * 0.125f : -1e9f; }
        MSK(0, s0) MSK(1, s1) MSK(2, s2) MSK(3, s3)
        #undef MSK
    }
    // softmax over cols (16 lanes), 4 rows in flight
    float m0=s0, m1=s1, m2=s2, m3=s3;
    #pragma unroll
    for (int off = 1; off < 16; off <<= 1) {
        m0 = fmaxf(m0, __shfl_xor(m0, off));
        m1 = fmaxf(m1, __shfl_xor(m1, off));
        m2 = fmaxf(m2, __shfl_xor(m2, off));
        m3 = fmaxf(m3, __shfl_xor(m3, off));
    }
    float e0=__expf(s0-m0), e1=__expf(s1-m1), e2=__expf(s2-m2), e3=__expf(s3-m3);
    float t0=e0, t1=e1, t2=e2, t3=e3;
    #pragma unroll
    for (int off = 1; off < 16; off <<= 1) {
        t0 += __shfl_xor(t0, off); t1 += __shfl_xor(t1, off);
        t2 += __shfl_xor(t2, off); t3 += __shfl_xor(t3, off);
    }
    // w[col] = sum_q maskq * attn[q][col]
    float wsum = __shfl(mkcol, grp*4 + 0) * (e0 / t0)
               + __shfl(mkcol, grp*4 + 1) * (e1 / t1)
               + __shfl(mkcol, grp*4 + 2) * (e2 / t2)
               + __shfl(mkcol, grp*4 + 3) * (e3 / t3);
    wsum += __shfl_xor(wsum, 16);
    wsum += __shfl_xor(wsum, 32);

    // denom per node
    float dn = mkcol;
    dn += __shfl_xor(dn, 1); dn += __shfl_xor(dn, 2); dn += __shfl_xor(dn, 4);
    const float dnA = fmaxf(__shfl(dn, 0), 1.f);
    const float dnB = fmaxf(__shfl(dn, 8), 1.f);

    // pooled from registers (fp32), lane = d
    float pA = 0.f, pB = 0.f;
    #pragma unroll
    for (int k = 0; k < 8; ++k) {
        pA += __shfl(wsum, k)     * ein_r[k];
        pB += __shfl(wsum, 8 + k) * ein_r[8 + k];
    }
    const size_t pbase = (size_t)(n0 - nodeBase) * D;
    pooled[pbase + lane]     = f2bf(pA / dnA);   // node n0
    pooled[pbase + D + lane] = f2bf(pB / dnB);   // node n0+1
}

// ================= Kernel B: MLP over 128 rows/block ========================
__global__ __launch_bounds__(256, 4) void mlp_kernel(
    const float* __restrict__ edges,
    const int*   __restrict__ out_idx,
    const int*   __restrict__ out_mask,
    const float* __restrict__ b0, const float* __restrict__ b1,
    const float* __restrict__ Wout, const float* __restrict__ bout,
    const unsigned short* __restrict__ Wbf,     // [2][128][128] bf16
    const unsigned short* __restrict__ pooled,  // chunk-local
    float* __restrict__ out,
    int nodeBase, int nodeEnd)
{
    __shared__ __align__(16) unsigned short xbuf[BROWS][XLDB];  // 34816 B
    const int tid  = threadIdx.x;
    const int wave = tid >> 6;
    const int lane = tid & 63;
    const int rowBase = (nodeBase + blockIdx.x * 32) * KOUT;    // global row
    const int rowEnd  = nodeEnd * KOUT;

    // ---- stage x = [Eout | pooled], 32 rows per wave (coalesced per row) ----
    #pragma unroll 4
    for (int rr = 0; rr < 32; ++rr) {
        const int row  = wave * 32 + rr;
        const int grow = rowBase + row;
        if (grow < rowEnd) {
            const int n  = grow >> 2;                  // node of this row
            const int oi = out_idx[grow];              // wave-uniform scalar load
            xbuf[row][lane]     = f2bf(edges[(size_t)oi * D + lane]);
            xbuf[row][D + lane] = pooled[(size_t)(n - nodeBase) * D + lane];
        }
    }
    __syncthreads();

    // ---- two 128x128x128 bf16-MFMA layers; wave = 4 row-tiles x 4 col-tiles -
    const int l15  = lane & 15;
    const int kofs = (lane >> 4) * 8;
    const int rrow = (lane >> 4) * 4;
    const int rowb = (wave >> 1) * 64;
    const int colb = (wave & 1) * 64;

    #pragma unroll
    for (int layer = 0; layer < 2; ++layer) {
        const unsigned short* __restrict__ Wl = Wbf + layer * (H*H);
        const float* __restrict__ bl = layer ? b1 : b0;

        f32x4 acc[4][4];
        #pragma unroll
        for (int ct = 0; ct < 4; ++ct) {
            const float bv = bl[colb + ct*16 + l15];
            #pragma unroll
            for (int rt = 0; rt < 4; ++rt) acc[rt][ct] = (f32x4){bv, bv, bv, bv};
        }
        #pragma unroll
        for (int ks = 0; ks < 4; ++ks) {
            short8v bfr[4];
            #pragma unroll
            for (int ct = 0; ct < 4; ++ct)
                bfr[ct] = *(const short8v*)&Wl[(size_t)(colb + ct*16 + l15) * H + ks*32 + kofs];
            #pragma unroll
            for (int rt = 0; rt < 4; ++rt) {
                const short8v a = *(const short8v*)&xbuf[rowb + rt*16 + l15][ks*32 + kofs];
                #pragma unroll
                for (int ct = 0; ct < 4; ++ct)
                    acc[rt][ct] = __builtin_amdgcn_mfma_f32_16x16x32_bf16(a, bfr[ct], acc[rt][ct], 0, 0, 0);
            }
        }
        __syncthreads();   // all A-reads of xbuf complete
        #pragma unroll
        for (int rt = 0; rt < 4; ++rt)
            #pragma unroll
            for (int ct = 0; ct < 4; ++ct)
                #pragma unroll
                for (int j = 0; j < 4; ++j)
                    xbuf[rowb + rt*16 + rrow + j][colb + ct*16 + l15] =
                        f2bf(fmaxf(acc[rt][ct][j], 0.f));
        __syncthreads();
    }

    // ---- epilogue: y = h1 . Wout + bout, masked; 2 threads per row ---------
    {
        const int row = tid >> 1;          // 0..127
        const int kh  = tid & 1;           // k-half (64 each)
        float p = 0.f;
        #pragma unroll
        for (int m = 0; m < 8; ++m) {
            const int k0 = kh*64 + m*8;
            const short8v hv = *(const short8v*)&xbuf[row][k0];
            const float4 w0 = *(const float4*)&Wout[k0];
            const float4 w1 = *(const float4*)&Wout[k0 + 4];
            union { unsigned u; float f; } c;
            c.u = ((unsigned)(unsigned short)hv[0]) << 16; p += c.f * w0.x;
            c.u = ((unsigned)(unsigned short)hv[1]) << 16; p += c.f * w0.y;
            c.u = ((unsigned)(unsigned short)hv[2]) << 16; p += c.f * w0.z;
            c.u = ((unsigned)(unsigned short)hv[3]) << 16; p += c.f * w0.w;
            c.u = ((unsigned)(unsigned short)hv[4]) << 16; p += c.f * w1.x;
            c.u = ((unsigned)(unsigned short)hv[5]) << 16; p += c.f * w1.y;
            c.u = ((unsigned)(unsigned short)hv[6]) << 16; p += c.f * w1.z;
            c.u = ((unsigned)(unsigned short)hv[7]) << 16; p += c.f * w1.w;
        }
        p += __shfl_xor(p, 1);
        const int grow = rowBase + row;
        if (kh == 0 && grow < rowEnd)
            out[grow] = (p + bout[0]) * (float)out_mask[grow];
    }
}

extern "C" void kernel_launch(void* const* d_in, const int* in_sizes, int n_in,
                              void* d_out, int out_size, void* d_ws, size_t ws_size,
                              hipStream_t stream)
{
    const float* edges  = (const float*)d_in[0];
    const int* in_idx   = (const int*)d_in[1];
    const int* in_mask  = (const int*)d_in[2];
    const int* out_idx  = (const int*)d_in[3];
    const int* out_mask = (const int*)d_in[4];
    const float* W0   = (const float*)d_in[5];
    const float* b0   = (const float*)d_in[6];
    const float* W1   = (const float*)d_in[7];
    const float* b1   = (const float*)d_in[8];
    const float* Wout = (const float*)d_in[9];
    const float* bout = (const float*)d_in[10];
    float* out = (float*)d_out;

    unsigned short* Wbf       = (unsigned short*)d_ws;                  // 64 KB
    unsigned short* pooledBuf = (unsigned short*)((char*)d_ws + 65536);

    const int nNodes = in_sizes[1] / KIN;               // 200000
    convert_w_kernel<<<(2*H*H + 255) / 256, 256, 0, stream>>>(W0, W1, Wbf);

    // chunk nodes so pooled fits in remaining ws (128 B/node); usually 1 chunk
    const size_t avail = (ws_size > 65536) ? ws_size - 65536 : 0;
    long long maxNodes = (long long)(avail / (D * sizeof(unsigned short)));
    int chunk = (int)((maxNodes / 32) * 32);
    if (chunk <= 0) chunk = 32;
    if (chunk > nNodes) chunk = nNodes;

    for (int base = 0; base < nNodes; base += chunk) {
        const int end = (base + chunk < nNodes) ? base + chunk : nNodes;
        const int cn  = end - base;
        attn_kernel<<<(cn + 7) / 8, 256, 0, stream>>>(
            edges, in_idx, in_mask, pooledBuf, base, end);
        mlp_kernel<<<(cn + 31) / 32, 256, 0, stream>>>(
            edges, out_idx, out_mask, b0, b1, Wout, bout,
            Wbf, pooledBuf, out, base, end);
    }
}